// Round 1
// 468.230 us; speedup vs baseline: 1.0159x; 1.0159x over previous
//
#include <hip/hip_runtime.h>
#include <math.h>

namespace {

constexpr int B_ = 4;
constexpr int C_ = 256;
constexpr int C4_ = 64;
constexpr int N_ = 4096;

typedef __attribute__((ext_vector_type(8))) short bf16x8;
typedef __attribute__((ext_vector_type(4))) float f32x4;

__device__ __forceinline__ unsigned short bf16_rne(float f) {
    unsigned u = __float_as_uint(f);
    u += 0x7fffu + ((u >> 16) & 1u);
    return (unsigned short)(u >> 16);
}

// Convert wq||wv -> wcomb bf16 [320,256], wt -> wtb bf16 [256,256].
__global__ __launch_bounds__(256) void cvt_kernel(
        const float* __restrict__ wq, const float* __restrict__ wv,
        const float* __restrict__ wt, unsigned short* __restrict__ wcomb,
        unsigned short* __restrict__ wtb) {
    const int i = (blockIdx.x * 256 + threadIdx.x) * 4;
    const float* src;
    unsigned short* dst;
    if (i < 16384) { src = wq + i; dst = wcomb + i; }
    else if (i < 81920) { src = wv + (i - 16384); dst = wcomb + i; }
    else { src = wt + (i - 81920); dst = wtb + (i - 81920); }
    const float4 f = *reinterpret_cast<const float4*>(src);
    ushort4 u;
    u.x = bf16_rne(f.x); u.y = bf16_rne(f.y);
    u.z = bf16_rne(f.z); u.w = bf16_rne(f.w);
    *reinterpret_cast<ushort4*>(dst) = u;
}

// MFMA projection: one 1024-thread block per 64-n tile; 16 waves = 4 n-strips
// x 4 o-quarters (5 ot each). x staged once per block.
__global__ __launch_bounds__(1024, 4) void proj_kernel(
        const float* __restrict__ x, const unsigned short* __restrict__ wcomb,
        const float* __restrict__ bv, unsigned short* __restrict__ qkT,
        unsigned short* __restrict__ v) {
    __shared__ unsigned short xs[2][64][40];
    const int b = blockIdx.y;
    const int n0 = blockIdx.x * 64;
    const int tid = threadIdx.x;
    const int wave = tid >> 6, lane = tid & 63;
    const int ws = wave & 3, oq = wave >> 2;
    const int quad = lane >> 4, l15 = lane & 15;
    const int ca = tid >> 6, na = tid & 63;
    const int cb = (tid + 1024) >> 6, nb2 = (tid + 1024) & 63;
    f32x4 acc[5];
#pragma unroll
    for (int ot = 0; ot < 5; ++ot) acc[ot] = (f32x4){0.f, 0.f, 0.f, 0.f};
    xs[0][na][ca] = bf16_rne(x[((size_t)b * C_ + ca) * N_ + n0 + na]);
    xs[0][nb2][cb] = bf16_rne(x[((size_t)b * C_ + cb) * N_ + n0 + nb2]);
    __syncthreads();
    for (int ch = 0; ch < 8; ++ch) {
        const int buf = ch & 1;
        float la = 0.f, lb = 0.f;
        if (ch < 7) {
            la = x[((size_t)b * C_ + (ch + 1) * 32 + ca) * N_ + n0 + na];
            lb = x[((size_t)b * C_ + (ch + 1) * 32 + cb) * N_ + n0 + nb2];
        }
        const bf16x8 a = *reinterpret_cast<const bf16x8*>(&xs[buf][ws * 16 + l15][quad * 8]);
#pragma unroll
        for (int ot = 0; ot < 5; ++ot) {
            const int gro = oq * 5 + ot;
            const bf16x8 wb = *reinterpret_cast<const bf16x8*>(
                wcomb + (size_t)(gro * 16 + l15) * C_ + ch * 32 + quad * 8);
            acc[ot] = __builtin_amdgcn_mfma_f32_16x16x32_bf16(a, wb, acc[ot], 0, 0, 0);
        }
        if (ch < 7) {
            xs[buf ^ 1][na][ca] = bf16_rne(la);
            xs[buf ^ 1][nb2][cb] = bf16_rne(lb);
        }
        __syncthreads();
    }
    const int n = n0 + ws * 16 + quad * 4;
#pragma unroll
    for (int ot = 0; ot < 5; ++ot) {
        const int gro = oq * 5 + ot;
        if (gro < 4) {
            const int o = gro * 16 + l15;
#pragma unroll
            for (int r = 0; r < 4; ++r)
                qkT[((size_t)b * N_ + n + r) * C4_ + o] = bf16_rne(acc[ot][r]);
        } else {
            const int c = (gro - 4) * 16 + l15;
            const float bb = bv[c];
            ushort4 u;
            u.x = bf16_rne(acc[ot][0] + bb);
            u.y = bf16_rne(acc[ot][1] + bb);
            u.z = bf16_rne(acc[ot][2] + bb);
            u.w = bf16_rne(acc[ot][3] + bb);
            *reinterpret_cast<ushort4*>(&v[((size_t)b * C_ + c) * N_ + n]) = u;
        }
    }
}

// rowsuminv[b,n] = 1/sum_m exp(e[n,m]). 16 waves = 4 n-strips x 4 m-subtiles,
// all walking the same m-tile staged into LDS (dbuf) with coalesced loads.
__global__ __launch_bounds__(1024, 4) void rowsum_kernel(
        const unsigned short* __restrict__ qkT, float* __restrict__ rowsuminv) {
    __shared__ unsigned short kt[2][64][68];
    __shared__ float red[4][4][16];
    const int b = blockIdx.y;
    const int tid = threadIdx.x;
    const int wave = tid >> 6, lane = tid & 63;
    const int ws = wave & 3, sg = wave >> 2;
    const int quad = lane >> 4, l15 = lane & 15;
    const int n0 = blockIdx.x * 64;
    const unsigned short* qb = qkT + (size_t)b * N_ * C4_;
    const unsigned short* qrow = qb + (size_t)(n0 + ws * 16 + l15) * C4_;
    const bf16x8 a0 = *reinterpret_cast<const bf16x8*>(qrow + quad * 8);
    const bf16x8 a1 = *reinterpret_cast<const bf16x8*>(qrow + 32 + quad * 8);
    const int srow = tid >> 3, soff = tid & 7;
    if (tid < 512) {
        const bf16x8 sk = *reinterpret_cast<const bf16x8*>(qb + (size_t)srow * C4_ + soff * 8);
        *reinterpret_cast<bf16x8*>(&kt[0][srow][soff * 8]) = sk;
    }
    __syncthreads();
    float cs[4] = {};
    for (int mt = 0; mt < 64; ++mt) {
        const int buf = mt & 1;
        bf16x8 nk;
        if (mt < 63 && tid < 512)
            nk = *reinterpret_cast<const bf16x8*>(
                qb + (size_t)((mt + 1) * 64 + srow) * C4_ + soff * 8);
        const bf16x8 kb0 = *reinterpret_cast<const bf16x8*>(&kt[buf][sg * 16 + l15][quad * 8]);
        const bf16x8 kb1 = *reinterpret_cast<const bf16x8*>(&kt[buf][sg * 16 + l15][32 + quad * 8]);
        f32x4 z = {0.f, 0.f, 0.f, 0.f};
        z = __builtin_amdgcn_mfma_f32_16x16x32_bf16(a0, kb0, z, 0, 0, 0);
        const f32x4 e = __builtin_amdgcn_mfma_f32_16x16x32_bf16(a1, kb1, z, 0, 0, 0);
#pragma unroll
        for (int r = 0; r < 4; ++r) cs[r] += __expf(e[r]);
        if (mt < 63 && tid < 512)
            *reinterpret_cast<bf16x8*>(&kt[buf ^ 1][srow][soff * 8]) = nk;
        __syncthreads();
    }
#pragma unroll
    for (int r = 0; r < 4; ++r) {
#pragma unroll
        for (int k = 1; k <= 8; k <<= 1) cs[r] += __shfl_xor(cs[r], k, 64);
        if (l15 == 0) red[sg][ws][quad * 4 + r] = cs[r];
    }
    __syncthreads();
    if (tid < 64) {
        const int ws2 = tid >> 4, row = tid & 15;
        const float sum = red[0][ws2][row] + red[1][ws2][row] +
                          red[2][ws2][row] + red[3][ws2][row];
        rowsuminv[(size_t)b * N_ + n0 + ws2 * 16 + row] = 1.0f / sum;
    }
}

// colsuminv[b,m] = 1/(1e-9 + sum_n exp(e[n,m])*rowsuminv[n]).
// 16 waves = 4 m-strips (kb in regs) x 4 n-subtiles of the staged q-tile.
__global__ __launch_bounds__(1024, 4) void colsum_kernel(
        const unsigned short* __restrict__ qkT, const float* __restrict__ rowsuminv,
        float* __restrict__ colsuminv) {
    __shared__ float rl[N_];
    __shared__ unsigned short qt[2][64][68];
    __shared__ float red[4][4][16];
    const int b = blockIdx.y;
    const int tid = threadIdx.x;
    const int wave = tid >> 6, lane = tid & 63;
    const int mw = wave & 3, ng = wave >> 2;
    const int quad = lane >> 4, l15 = lane & 15;
    const int m0 = blockIdx.x * 64;
    for (int i = tid; i < N_; i += 1024) rl[i] = rowsuminv[(size_t)b * N_ + i];
    const unsigned short* qb = qkT + (size_t)b * N_ * C4_;
    const unsigned short* krow = qb + (size_t)(m0 + mw * 16 + l15) * C4_;
    const bf16x8 kb0 = *reinterpret_cast<const bf16x8*>(krow + quad * 8);
    const bf16x8 kb1 = *reinterpret_cast<const bf16x8*>(krow + 32 + quad * 8);
    const int srow = tid >> 3, soff = tid & 7;
    if (tid < 512) {
        const bf16x8 sq = *reinterpret_cast<const bf16x8*>(qb + (size_t)srow * C4_ + soff * 8);
        *reinterpret_cast<bf16x8*>(&qt[0][srow][soff * 8]) = sq;
    }
    __syncthreads();
    float cs = 0.f;
    for (int nt = 0; nt < 64; ++nt) {
        const int buf = nt & 1;
        bf16x8 nq;
        if (nt < 63 && tid < 512)
            nq = *reinterpret_cast<const bf16x8*>(
                qb + (size_t)((nt + 1) * 64 + srow) * C4_ + soff * 8);
        const bf16x8 a0 = *reinterpret_cast<const bf16x8*>(&qt[buf][ng * 16 + l15][quad * 8]);
        const bf16x8 a1 = *reinterpret_cast<const bf16x8*>(&qt[buf][ng * 16 + l15][32 + quad * 8]);
        f32x4 z = {0.f, 0.f, 0.f, 0.f};
        z = __builtin_amdgcn_mfma_f32_16x16x32_bf16(a0, kb0, z, 0, 0, 0);
        const f32x4 e = __builtin_amdgcn_mfma_f32_16x16x32_bf16(a1, kb1, z, 0, 0, 0);
        const int nb = nt * 64 + ng * 16 + quad * 4;
#pragma unroll
        for (int r = 0; r < 4; ++r) cs += __expf(e[r]) * rl[nb + r];
        if (nt < 63 && tid < 512)
            *reinterpret_cast<bf16x8*>(&qt[buf ^ 1][srow][soff * 8]) = nq;
        __syncthreads();
    }
    cs += __shfl_xor(cs, 16, 64);
    cs += __shfl_xor(cs, 32, 64);
    if (quad == 0) red[ng][mw][l15] = cs;
    __syncthreads();
    if (tid < 64) {
        const int mw2 = tid >> 4, l = tid & 15;
        const float sum = red[0][mw2][l] + red[1][mw2][l] +
                          red[2][mw2][l] + red[3][mw2][l];
        colsuminv[(size_t)b * N_ + m0 + mw2 * 16 + l] = 1.0f / (1e-9f + sum);
    }
}

// Final: barrier-free m-loop. 16 waves = 4 n-strips (ws) x 4 m-quarters (grp).
// Each wave: swapped-operand energy (mfma(K,Q)) so p-rows are lane-local,
// p round-trips through a WAVE-PRIVATE LDS tile (no cross-wave sync), PV
// accumulates all 256 channels over the wave's 1024-m range with v read
// directly from global (L2-resident; full-64B-line loads). Epilogue: 4-phase
// f32 reduce over m-partials, then dsm -> wt GEMM -> BN -> relu (unchanged).
// XCD-batch swizzle: batch b -> XCD pair {2b,2b+1} so v+qkT fit per-XCD L2.
__global__ __launch_bounds__(1024, 4) void final_kernel(
        const float* __restrict__ x, const unsigned short* __restrict__ qkT,
        const unsigned short* __restrict__ v, const unsigned short* __restrict__ wtb,
        const float* __restrict__ rowsuminv, const float* __restrict__ colsuminv,
        const float* __restrict__ bt, const float* __restrict__ gamma,
        const float* __restrict__ beta, const float* __restrict__ rmean,
        const float* __restrict__ rvar, float* __restrict__ out) {
    __shared__ unsigned short pw[16][16][72];   // 36.9 KB wave-private p tiles
    __shared__ float xr[64][258];               // 66.0 KB f32 x_r reduce buffer
    __shared__ unsigned short dsm[64][268];     // 34.3 KB x - x_r (bf16)
    const int gid = blockIdx.x;
    const int xcd = gid & 7;
    const int b = xcd >> 1;                       // batch -> XCD pair
    const int n0 = ((((unsigned)gid >> 3) << 1) | (xcd & 1)) * 64;
    const int tid = threadIdx.x;
    const int wave = tid >> 6, lane = tid & 63;
    const int ws = wave & 3, grp = wave >> 2;
    const int quad = lane >> 4, l15 = lane & 15;
    const unsigned short* qb = qkT + (size_t)b * N_ * C4_;
    const unsigned short* qrow = qb + (size_t)(n0 + ws * 16 + l15) * C4_;
    const bf16x8 q0 = *reinterpret_cast<const bf16x8*>(qrow + quad * 8);
    const bf16x8 q1 = *reinterpret_cast<const bf16x8*>(qrow + 32 + quad * 8);
    const float rli = rowsuminv[(size_t)b * N_ + n0 + ws * 16 + l15];
    const unsigned short* vbg = v + (size_t)b * C_ * N_;
    const float* civb = colsuminv + (size_t)b * N_;
    f32x4 acc[16];
#pragma unroll
    for (int j = 0; j < 16; ++j) acc[j] = (f32x4){0.f, 0.f, 0.f, 0.f};
    const int mbase = grp * 1024;
#pragma unroll 1
    for (int mt = 0; mt < 16; ++mt) {
        const int m0 = mbase + mt * 64;
        // Energy (swapped: A = K-tile rows m, B = Q cols n). Per lane after
        // both K-steps: e[n = l15][m = m0 + ch*16 + quad*4 + r].
#pragma unroll
        for (int ch = 0; ch < 4; ++ch) {
            const unsigned short* krow = qb + (size_t)(m0 + ch * 16 + l15) * C4_;
            const bf16x8 ka0 = *reinterpret_cast<const bf16x8*>(krow + quad * 8);
            const bf16x8 ka1 = *reinterpret_cast<const bf16x8*>(krow + 32 + quad * 8);
            f32x4 z = {0.f, 0.f, 0.f, 0.f};
            z = __builtin_amdgcn_mfma_f32_16x16x32_bf16(ka0, q0, z, 0, 0, 0);
            z = __builtin_amdgcn_mfma_f32_16x16x32_bf16(ka1, q1, z, 0, 0, 0);
            const float4 civ = *reinterpret_cast<const float4*>(civb + m0 + ch * 16 + quad * 4);
            ushort4 pk;
            pk.x = bf16_rne(__expf(z[0]) * rli * civ.x);
            pk.y = bf16_rne(__expf(z[1]) * rli * civ.y);
            pk.z = bf16_rne(__expf(z[2]) * rli * civ.z);
            pk.w = bf16_rne(__expf(z[3]) * rli * civ.w);
            *reinterpret_cast<ushort4*>(&pw[wave][l15][ch * 16 + quad * 4]) = pk;
        }
        // PV: A = p[n][m] from wave-private LDS, B = v[c][m] direct from global.
        const bf16x8 pa0 = *reinterpret_cast<const bf16x8*>(&pw[wave][l15][quad * 8]);
        const bf16x8 pa1 = *reinterpret_cast<const bf16x8*>(&pw[wave][l15][32 + quad * 8]);
#pragma unroll
        for (int j = 0; j < 16; ++j) {
            const unsigned short* vrow = vbg + (size_t)(j * 16 + l15) * N_ + m0;
            const bf16x8 vb0 = *reinterpret_cast<const bf16x8*>(vrow + quad * 8);
            const bf16x8 vb1 = *reinterpret_cast<const bf16x8*>(vrow + 32 + quad * 8);
            acc[j] = __builtin_amdgcn_mfma_f32_16x16x32_bf16(pa0, vb0, acc[j], 0, 0, 0);
            acc[j] = __builtin_amdgcn_mfma_f32_16x16x32_bf16(pa1, vb1, acc[j], 0, 0, 0);
        }
    }
    // Cross-grp (m-partition) f32 reduction: acc[j][r] = x_r[n=quad*4+r][c=j*16+l15].
    for (int ph = 0; ph < 4; ++ph) {
        __syncthreads();
        if (grp == ph) {
#pragma unroll
            for (int j = 0; j < 16; ++j) {
#pragma unroll
                for (int r = 0; r < 4; ++r) {
                    float* d = &xr[ws * 16 + quad * 4 + r][j * 16 + l15];
                    if (ph == 0) *d = acc[j][r];
                    else *d += acc[j][r];
                }
            }
        }
    }
    __syncthreads();
    // dsm = x - x_r (bf16); wave w handles channel rows [16w, 16w+16).
#pragma unroll
    for (int cc = 0; cc < 16; ++cc) {
        const int c = wave * 16 + cc;
        const float xv = x[((size_t)b * C_ + c) * N_ + n0 + lane];
        dsm[lane][c] = bf16_rne(xv - xr[lane][c]);
    }
    __syncthreads();
    // wt GEMM: 4 strips x 4 o-quarters
    bf16x8 da[8];
#pragma unroll
    for (int k = 0; k < 8; ++k)
        da[k] = *reinterpret_cast<const bf16x8*>(&dsm[ws * 16 + l15][k * 32 + quad * 8]);
    f32x4 tacc[4];
#pragma unroll
    for (int j = 0; j < 4; ++j) tacc[j] = (f32x4){0.f, 0.f, 0.f, 0.f};
#pragma unroll
    for (int j = 0; j < 4; ++j) {
        const int ot = grp * 4 + j;
#pragma unroll
        for (int k = 0; k < 8; ++k) {
            const bf16x8 wb = *reinterpret_cast<const bf16x8*>(
                wtb + (size_t)(ot * 16 + l15) * C_ + k * 32 + quad * 8);
            tacc[j] = __builtin_amdgcn_mfma_f32_16x16x32_bf16(da[k], wb, tacc[j], 0, 0, 0);
        }
    }
#pragma unroll
    for (int j = 0; j < 4; ++j) {
        const int o = (grp * 4 + j) * 16 + l15;
        const float g = gamma[o] * rsqrtf(rvar[o] + 1e-5f);
        const float mn = rmean[o], bbet = beta[o], bo = bt[o];
        const size_t oi = ((size_t)b * C_ + o) * N_ + n0 + ws * 16 + quad * 4;
        const float4 xo = *reinterpret_cast<const float4*>(&x[oi]);
        float4 res;
        res.x = xo.x + fmaxf((tacc[j][0] + bo - mn) * g + bbet, 0.f);
        res.y = xo.y + fmaxf((tacc[j][1] + bo - mn) * g + bbet, 0.f);
        res.z = xo.z + fmaxf((tacc[j][2] + bo - mn) * g + bbet, 0.f);
        res.w = xo.w + fmaxf((tacc[j][3] + bo - mn) * g + bbet, 0.f);
        *reinterpret_cast<float4*>(&out[oi]) = res;
    }
}

}  // namespace

extern "C" void kernel_launch(void* const* d_in, const int* in_sizes, int n_in,
                              void* d_out, int out_size, void* d_ws, size_t ws_size,
                              hipStream_t stream) {
    const float* x = (const float*)d_in[0];
    const float* wq = (const float*)d_in[1];
    const float* wv = (const float*)d_in[2];
    const float* bv = (const float*)d_in[3];
    const float* wt = (const float*)d_in[4];
    const float* bt = (const float*)d_in[5];
    const float* gamma = (const float*)d_in[6];
    const float* beta = (const float*)d_in[7];
    const float* rmean = (const float*)d_in[8];
    const float* rvar = (const float*)d_in[9];
    float* out = (float*)d_out;

    char* base = (char*)d_ws;
    unsigned short* qkT = (unsigned short*)base;                        // 2 MB
    unsigned short* vw = (unsigned short*)(base + (2u << 20));          // 8 MB
    unsigned short* wtb = (unsigned short*)(base + (10u << 20));        // 128 KB
    unsigned short* wcomb = (unsigned short*)(base + (10u << 20) + (128u << 10));
    float* rowsuminv = (float*)(base + (10u << 20) + (288u << 10));     // 64 KB
    float* colsuminv = (float*)(base + (10u << 20) + (352u << 10));     // 64 KB

    cvt_kernel<<<dim3(144), dim3(256), 0, stream>>>(wq, wv, wt, wcomb, wtb);
    proj_kernel<<<dim3(N_ / 64, B_), dim3(1024), 0, stream>>>(x, wcomb, bv, qkT, vw);
    rowsum_kernel<<<dim3(N_ / 64, B_), dim3(1024), 0, stream>>>(qkT, rowsuminv);
    colsum_kernel<<<dim3(N_ / 64, B_), dim3(1024), 0, stream>>>(qkT, rowsuminv, colsuminv);
    final_kernel<<<dim3(N_ / 64 * B_), dim3(1024), 0, stream>>>(
        x, qkT, vw, wtb, rowsuminv, colsuminv, bt, gamma, beta, rmean, rvar, out);
}